// Round 6
// baseline (702.249 us; speedup 1.0000x reference)
//
#include <hip/hip_runtime.h>

typedef _Float16 half8 __attribute__((ext_vector_type(8)));
typedef float f32x4 __attribute__((ext_vector_type(4)));

#define B_TOTAL 32768
#define T 7
#define F 36
#define U 256
#define G4 1024
#define BM 64
#define KC 10          // K chunks of 32: kc 0..7 = h (K=256), kc 8..9 = x (F=36 padded to 64)
#define KPACK 32
#define H_STRIDE 264   // halves; 264*2=528 B rows, 16B-aligned
#define XS 72          // halves per (t,row) in xs plane; 144 B stride
#define WKC (16 * 4 * 16 * KPACK)   // halves per kc plane = 32768 (64 KB)

// W layout: Wq[kc][w][g][l15][kin]  (col n = g*256 + w*16 + l15, k = kc*32 + kin)
// -> per (wave,kc) the 4 gate-fragments are contiguous: one pointer, imm offsets
//    g*1024B; kc stride 64 KB. W = [Wr(256 rows); Wk(36); zeros(28)].
__global__ __launch_bounds__(1024) void pack_w(const float* __restrict__ Wr,
                                               const float* __restrict__ Wk,
                                               _Float16* __restrict__ Wq) {
    const int kc   = blockIdx.x >> 2;
    const int kin0 = (blockIdx.x & 3) * 8;
    const int n    = threadIdx.x;          // n = g*256 + w*16 + l15
    const int g    = n >> 8;
    const int w    = (n >> 4) & 15;
    const int l15  = n & 15;
    _Float16* dst = Wq + ((size_t)((kc * 16 + w) * 4 + g) * 16 + l15) * KPACK + kin0;
    #pragma unroll
    for (int j = 0; j < 8; ++j) {
        int k = kc * KPACK + kin0 + j;
        float v = 0.f;
        if (k < U)          v = Wr[(size_t)k * G4 + n];
        else if (k < U + F) v = Wk[(size_t)(k - U) * G4 + n];
        dst[j] = (_Float16)v;
    }
}

__device__ __forceinline__ float fast_sigmoid(float x) {
    return __builtin_amdgcn_rcpf(1.f + __expf(-x));
}
__device__ __forceinline__ float fast_tanh(float x) {
    return 1.f - 2.f * __builtin_amdgcn_rcpf(1.f + __expf(2.f * x));
}

// Persistent LSTM: one 16-wave block owns BM=64 batch rows for all T=7 steps.
// Wave w owns u-range [16w,16w+16) x 4 gates x all 64 rows.
// Deltas vs round 5 (275us, traffic-clean): x-contribution (kc 8,9, h-independent)
// for step t+1 computed BEFORE the barrier (overlaps gates-VALU of other waves,
// post-barrier critical path = 128 MFMA not 160); W regrouped per-wave so the
// 4 gate fragments / kc are one pointer + imm offsets; h-loop fully unrolled.
__global__ __launch_bounds__(1024, 4) void lstm_kernel(
    const float* __restrict__ x,      // [B,T,F]
    const float* __restrict__ h0,     // [B,U]
    const float* __restrict__ c0,     // [B,U]
    const _Float16* __restrict__ Wq,  // packed [KC][16][4][16][KPACK]
    const float* __restrict__ bias_g, // [G4]
    float* __restrict__ out)          // [B,T,U]
{
    __shared__ __align__(16) _Float16 hbuf[2][BM * H_STRIDE];  // 2 x 33.8 KB
    __shared__ __align__(16) _Float16 xs[T * BM * XS];          // 64.5 KB

    const int tid  = threadIdx.x;
    const int lane = tid & 63;
    const int w    = tid >> 6;     // wave id 0..15 = u-tile
    const int l15  = lane & 15;
    const int q    = lane >> 4;    // 0..3
    const int u0   = w * 16;
    const int b0   = blockIdx.x * BM;

    // --- zero xs (covers the f=36..63 pad the MFMA reads, and row pad) ---
    {
        half8 z = {};
        for (int i = tid * 8; i < T * BM * XS; i += 1024 * 8)
            *(half8*)&xs[i] = z;
    }
    __syncthreads();   // zero visible before fill

    // --- stage h0 -> LDS fp16 ---
    for (int i = tid; i < BM * U; i += 1024) {
        int m = i >> 8, u = i & 255;
        hbuf[0][m * H_STRIDE + u] = (_Float16)h0[(size_t)b0 * U + i];
    }
    // --- stage ALL x for this block's rows (contiguous 64KB global read) ---
    for (int i = tid; i < BM * (T * F); i += 1024) {
        int row = i / (T * F);
        int rem = i - row * (T * F);
        int t   = rem / F;
        int f   = rem - t * F;
        xs[(t * BM + row) * XS + f] = (_Float16)x[(size_t)(b0 + row) * (T * F) + rem];
    }
    // --- c0 into registers: lane holds (u = u0+l15) for rows mt*16+q*4+r ---
    float c[16];
    #pragma unroll
    for (int mt = 0; mt < 4; ++mt)
        #pragma unroll
        for (int r = 0; r < 4; ++r) {
            int row = mt * 16 + q * 4 + r;
            c[mt * 4 + r] = c0[(size_t)(b0 + row) * U + u0 + l15];
        }
    // --- bias per gate ---
    float bv[4];
    #pragma unroll
    for (int g = 0; g < 4; ++g) bv[g] = bias_g[g * U + u0 + l15];

    // per-lane W base (halves): wave slice + lane offset; kc stride WKC halves
    const _Float16* wp = Wq + ((size_t)(w * 4) * 16 + l15) * KPACK + q * 8;

    __syncthreads();   // staging complete

    f32x4 acc[4][4];   // [m_tile][gate]

    // --- x-part for step 0: acc = bias + x_0 @ Wk ---
    {
        #pragma unroll
        for (int mt = 0; mt < 4; ++mt)
            #pragma unroll
            for (int g = 0; g < 4; ++g)
                acc[mt][g] = (f32x4){bv[g], bv[g], bv[g], bv[g]};
        const _Float16* xbase = &xs[(size_t)l15 * XS + q * 8];
        #pragma unroll
        for (int kx = 8; kx < 10; ++kx) {
            half8 bf[4];
            #pragma unroll
            for (int g = 0; g < 4; ++g)
                bf[g] = *(const half8*)(wp + (size_t)kx * WKC + g * (16 * KPACK));
            #pragma unroll
            for (int mt = 0; mt < 4; ++mt) {
                half8 af = *(const half8*)(xbase + mt * 16 * XS + (kx - 8) * 32);
                #pragma unroll
                for (int g = 0; g < 4; ++g)
                    acc[mt][g] = __builtin_amdgcn_mfma_f32_16x16x32_f16(af, bf[g], acc[mt][g], 0, 0, 0);
            }
        }
    }

    int cur = 0;
    #pragma unroll 1
    for (int t = 0; t < T; ++t) {
        // --- h-part: acc += h_t @ Wr (kc 0..7, fully unrolled, imm LDS offsets) ---
        {
            const _Float16* hbase = &hbuf[cur][(size_t)l15 * H_STRIDE + q * 8];
            #pragma unroll
            for (int kc = 0; kc < 8; ++kc) {
                half8 bf[4];
                #pragma unroll
                for (int g = 0; g < 4; ++g)
                    bf[g] = *(const half8*)(wp + (size_t)kc * WKC + g * (16 * KPACK));
                #pragma unroll
                for (int mt = 0; mt < 4; ++mt) {
                    half8 af = *(const half8*)(hbase + mt * 16 * H_STRIDE + kc * 32);
                    #pragma unroll
                    for (int g = 0; g < 4; ++g)
                        acc[mt][g] = __builtin_amdgcn_mfma_f32_16x16x32_f16(af, bf[g], acc[mt][g], 0, 0, 0);
                }
            }
        }

        // --- gates: consume acc; write h_{t+1} fp16 to other LDS buffer ---
        const int nxt = cur ^ 1;
        #pragma unroll
        for (int mt = 0; mt < 4; ++mt)
            #pragma unroll
            for (int r = 0; r < 4; ++r) {
                float zi = acc[mt][0][r];
                float zf = acc[mt][1][r];
                float zg = acc[mt][2][r];
                float zo = acc[mt][3][r];
                float ig = fast_sigmoid(zi);
                float fg = fast_sigmoid(zf);
                float gg = fast_tanh(zg);
                float og = fast_sigmoid(zo);
                float cn = fg * c[mt * 4 + r] + ig * gg;
                c[mt * 4 + r] = cn;
                float hv = og * fast_tanh(cn);
                int row = mt * 16 + q * 4 + r;
                hbuf[nxt][row * H_STRIDE + u0 + l15] = (_Float16)hv;
            }

        // --- x-part for step t+1 (h-independent): re-init acc, accumulate x MFMAs.
        // Runs before the barrier -> overlaps other waves' gate VALU; shortens the
        // post-barrier h-critical-path to 128 MFMA. ---
        if (t + 1 < T) {
            #pragma unroll
            for (int mt = 0; mt < 4; ++mt)
                #pragma unroll
                for (int g = 0; g < 4; ++g)
                    acc[mt][g] = (f32x4){bv[g], bv[g], bv[g], bv[g]};
            const _Float16* xbase = &xs[((size_t)(t + 1) * BM + l15) * XS + q * 8];
            #pragma unroll
            for (int kx = 8; kx < 10; ++kx) {
                half8 bf[4];
                #pragma unroll
                for (int g = 0; g < 4; ++g)
                    bf[g] = *(const half8*)(wp + (size_t)kx * WKC + g * (16 * KPACK));
                #pragma unroll
                for (int mt = 0; mt < 4; ++mt) {
                    half8 af = *(const half8*)(xbase + mt * 16 * XS + (kx - 8) * 32);
                    #pragma unroll
                    for (int g = 0; g < 4; ++g)
                        acc[mt][g] = __builtin_amdgcn_mfma_f32_16x16x32_f16(af, bf[g], acc[mt][g], 0, 0, 0);
                }
            }
        }

        __syncthreads();   // h_{t+1} visible; h-part readers of hbuf[cur] done

        // --- coalesced out-store from hbuf[nxt]: consecutive tids -> consecutive
        // 32B -> full 128B lines. Fire-and-forget: overlaps next step's h-part.
        // Safe: next write to hbuf[nxt] is gates(t+2), one barrier + in-order LDS
        // pipeline past these reads (verified structure, rounds 0/5). ---
        #pragma unroll
        for (int rb = 0; rb < 2; ++rb) {
            int j   = tid + rb * 1024;      // 0..2047 chunks of 8 floats
            int row = j >> 5;
            int uo  = (j & 31) * 8;
            half8 hv = *(const half8*)&hbuf[nxt][row * H_STRIDE + uo];
            f32x4 lo = { (float)hv[0], (float)hv[1], (float)hv[2], (float)hv[3] };
            f32x4 hi = { (float)hv[4], (float)hv[5], (float)hv[6], (float)hv[7] };
            float* dst = out + ((size_t)(b0 + row) * T + t) * U + uo;
            *(f32x4*)dst       = lo;
            *(f32x4*)(dst + 4) = hi;
        }

        cur = nxt;
    }
}

extern "C" void kernel_launch(void* const* d_in, const int* in_sizes, int n_in,
                              void* d_out, int out_size, void* d_ws, size_t ws_size,
                              hipStream_t stream) {
    const float* x  = (const float*)d_in[0];
    const float* h0 = (const float*)d_in[1];
    const float* c0 = (const float*)d_in[2];
    const float* Wk = (const float*)d_in[3];
    const float* Wr = (const float*)d_in[4];
    const float* b  = (const float*)d_in[5];
    float* out = (float*)d_out;

    _Float16* Wq = (_Float16*)d_ws;   // KC*G4*KPACK*2 = 640 KB

    pack_w<<<KC * 4, 1024, 0, stream>>>(Wr, Wk, Wq);
    lstm_kernel<<<B_TOTAL / BM, 1024, 0, stream>>>(x, h0, c0, Wq, b, out);
}

// Round 10
// 544.959 us; speedup vs baseline: 1.2886x; 1.2886x over previous
//
#include <hip/hip_runtime.h>

typedef _Float16 half8 __attribute__((ext_vector_type(8)));
typedef float f32x4 __attribute__((ext_vector_type(4)));

#define B_TOTAL 32768
#define T 7
#define F 36
#define U 256
#define G4 1024
#define BM 64
#define KC 10          // K chunks of 32: kc 0..7 = h (K=256), kc 8..9 = x (F=36 padded to 64)
#define KPACK 32
#define H_STRIDE 264   // halves; 264*2=528 B rows, 16B-aligned
#define XS 72          // halves per (t,row) in xs plane; 144 B stride

// Round-0/5 verified W layout: Wq[kc][n][kin] fp16, n = gate*256 + u.
// W = [Wr (256 rows); Wk (36 rows); zeros (28 rows)].
__global__ __launch_bounds__(1024) void pack_w(const float* __restrict__ Wr,
                                               const float* __restrict__ Wk,
                                               _Float16* __restrict__ Wq) {
    const int kc   = blockIdx.x >> 2;
    const int kin0 = (blockIdx.x & 3) * 8;
    const int n    = threadIdx.x;
    _Float16* dst = Wq + ((size_t)kc * G4 + n) * KPACK + kin0;
    #pragma unroll
    for (int j = 0; j < 8; ++j) {
        int k = kc * KPACK + kin0 + j;
        float v = 0.f;
        if (k < U)          v = Wr[(size_t)k * G4 + n];
        else if (k < U + F) v = Wk[(size_t)(k - U) * G4 + n];
        dst[j] = (_Float16)v;
    }
}

__device__ __forceinline__ float fast_sigmoid(float x) {
    return __builtin_amdgcn_rcpf(1.f + __expf(-x));
}
__device__ __forceinline__ float fast_tanh(float x) {
    return 1.f - 2.f * __builtin_amdgcn_rcpf(1.f + __expf(2.f * x));
}

// Persistent LSTM, round-5 structure (275us verified, traffic-clean).
// Single delta vs round 5: K-loop split into h-part (kc 0..7) and x-part
// (kc 8..9); x-part of step t+1 runs after gates(t), BEFORE the barrier.
// x-part depends only on xs (stable) -> overlaps other waves' gate VALU and
// removes 32 of 160 MFMAs from the post-barrier critical path.
// NO full unroll of the h-loop (round-6 spill lesson): #pragma unroll 2 kept.
__global__ __launch_bounds__(1024) void lstm_kernel(
    const float* __restrict__ x,      // [B,T,F]
    const float* __restrict__ h0,     // [B,U]
    const float* __restrict__ c0,     // [B,U]
    const _Float16* __restrict__ Wq,  // packed [KC][G4][KPACK]
    const float* __restrict__ bias_g, // [G4]
    float* __restrict__ out)          // [B,T,U]
{
    __shared__ __align__(16) _Float16 hbuf[2][BM * H_STRIDE];  // 2 x 33.8 KB
    __shared__ __align__(16) _Float16 xs[T * BM * XS];          // 64.5 KB

    const int tid  = threadIdx.x;
    const int lane = tid & 63;
    const int w    = tid >> 6;     // wave id 0..15 = u-tile
    const int l15  = lane & 15;
    const int q    = lane >> 4;    // 0..3
    const int u0   = w * 16;
    const int b0   = blockIdx.x * BM;

    // --- zero xs (covers the f=36..63 pad the MFMA reads, and row pad) ---
    {
        half8 z = {};
        for (int i = tid * 8; i < T * BM * XS; i += 1024 * 8)
            *(half8*)&xs[i] = z;
    }
    __syncthreads();   // zero visible before fill

    // --- stage h0 -> LDS fp16 ---
    for (int i = tid; i < BM * U; i += 1024) {
        int m = i >> 8, u = i & 255;
        hbuf[0][m * H_STRIDE + u] = (_Float16)h0[(size_t)b0 * U + i];
    }
    // --- stage ALL x for this block's rows (contiguous 64KB global read) ---
    for (int i = tid; i < BM * (T * F); i += 1024) {
        int row = i / (T * F);
        int rem = i - row * (T * F);
        int t   = rem / F;
        int f   = rem - t * F;
        xs[(t * BM + row) * XS + f] = (_Float16)x[(size_t)(b0 + row) * (T * F) + rem];
    }
    // --- c0 into registers: lane holds (u = u0+l15) for rows mt*16+q*4+r ---
    float c[16];
    #pragma unroll
    for (int mt = 0; mt < 4; ++mt)
        #pragma unroll
        for (int r = 0; r < 4; ++r) {
            int row = mt * 16 + q * 4 + r;
            c[mt * 4 + r] = c0[(size_t)(b0 + row) * U + u0 + l15];
        }
    // --- bias per gate ---
    float bv[4];
    #pragma unroll
    for (int g = 0; g < 4; ++g) bv[g] = bias_g[g * U + u0 + l15];

    __syncthreads();   // staging complete

    f32x4 acc[4][4];   // [m_tile][gate]

    // --- prologue: acc = bias + x_0 @ Wk (kc 8,9) ---
    {
        #pragma unroll
        for (int mt = 0; mt < 4; ++mt)
            #pragma unroll
            for (int g = 0; g < 4; ++g)
                acc[mt][g] = (f32x4){bv[g], bv[g], bv[g], bv[g]};
        #pragma unroll
        for (int kx = 8; kx < 10; ++kx) {
            half8 bf[4];
            #pragma unroll
            for (int g = 0; g < 4; ++g) {
                size_t off = ((size_t)kx * G4 + g * U + u0 + l15) * KPACK + q * 8;
                bf[g] = *(const half8*)(Wq + off);
            }
            #pragma unroll
            for (int mt = 0; mt < 4; ++mt) {
                half8 af = *(const half8*)&xs[(size_t)(mt * 16 + l15) * XS + (kx - 8) * 32 + q * 8];
                #pragma unroll
                for (int g = 0; g < 4; ++g)
                    acc[mt][g] = __builtin_amdgcn_mfma_f32_16x16x32_f16(af, bf[g], acc[mt][g], 0, 0, 0);
            }
        }
    }

    int cur = 0;
    #pragma unroll 1
    for (int t = 0; t < T; ++t) {
        // --- h-part: acc += h_t @ Wr (kc 0..7; round-5 unroll discipline) ---
        #pragma unroll 2
        for (int kc = 0; kc < 8; ++kc) {
            half8 bf[4];
            #pragma unroll
            for (int g = 0; g < 4; ++g) {
                size_t off = ((size_t)kc * G4 + g * U + u0 + l15) * KPACK + q * 8;
                bf[g] = *(const half8*)(Wq + off);
            }
            #pragma unroll
            for (int mt = 0; mt < 4; ++mt) {
                half8 af = *(const half8*)&hbuf[cur][(mt * 16 + l15) * H_STRIDE + kc * 32 + q * 8];
                #pragma unroll
                for (int g = 0; g < 4; ++g)
                    acc[mt][g] = __builtin_amdgcn_mfma_f32_16x16x32_f16(af, bf[g], acc[mt][g], 0, 0, 0);
            }
        }

        // --- gates: consume acc; write h_{t+1} fp16 to other LDS buffer ---
        const int nxt = cur ^ 1;
        #pragma unroll
        for (int mt = 0; mt < 4; ++mt)
            #pragma unroll
            for (int r = 0; r < 4; ++r) {
                float zi = acc[mt][0][r];
                float zf = acc[mt][1][r];
                float zg = acc[mt][2][r];
                float zo = acc[mt][3][r];
                float ig = fast_sigmoid(zi);
                float fg = fast_sigmoid(zf);
                float gg = fast_tanh(zg);
                float og = fast_sigmoid(zo);
                float cn = fg * c[mt * 4 + r] + ig * gg;
                c[mt * 4 + r] = cn;
                float hv = og * fast_tanh(cn);
                int row = mt * 16 + q * 4 + r;
                hbuf[nxt][row * H_STRIDE + u0 + l15] = (_Float16)hv;
            }

        // --- x-part for step t+1 (h-independent): re-init acc with bias and
        // accumulate x MFMAs pre-barrier -> overlaps other waves' gate VALU. ---
        if (t + 1 < T) {
            #pragma unroll
            for (int mt = 0; mt < 4; ++mt)
                #pragma unroll
                for (int g = 0; g < 4; ++g)
                    acc[mt][g] = (f32x4){bv[g], bv[g], bv[g], bv[g]};
            #pragma unroll
            for (int kx = 8; kx < 10; ++kx) {
                half8 bf[4];
                #pragma unroll
                for (int g = 0; g < 4; ++g) {
                    size_t off = ((size_t)kx * G4 + g * U + u0 + l15) * KPACK + q * 8;
                    bf[g] = *(const half8*)(Wq + off);
                }
                #pragma unroll
                for (int mt = 0; mt < 4; ++mt) {
                    half8 af = *(const half8*)&xs[((size_t)(t + 1) * BM + mt * 16 + l15) * XS + (kx - 8) * 32 + q * 8];
                    #pragma unroll
                    for (int g = 0; g < 4; ++g)
                        acc[mt][g] = __builtin_amdgcn_mfma_f32_16x16x32_f16(af, bf[g], acc[mt][g], 0, 0, 0);
                }
            }
        }

        __syncthreads();   // h_{t+1} visible; h-part readers of hbuf[cur] done

        // --- coalesced out-store from hbuf[nxt] (round-5 verbatim): consecutive
        // tids -> consecutive 32B -> full 128B lines. Fire-and-forget: overlaps
        // next step's h-part; next write to hbuf[nxt] is gates(t+2), one barrier
        // past these (drained) reads. ---
        #pragma unroll
        for (int rb = 0; rb < 2; ++rb) {
            int j   = tid + rb * 1024;      // 0..2047 chunks of 8 floats
            int row = j >> 5;
            int uo  = (j & 31) * 8;
            half8 hv = *(const half8*)&hbuf[nxt][row * H_STRIDE + uo];
            f32x4 lo = { (float)hv[0], (float)hv[1], (float)hv[2], (float)hv[3] };
            f32x4 hi = { (float)hv[4], (float)hv[5], (float)hv[6], (float)hv[7] };
            float* dst = out + ((size_t)(b0 + row) * T + t) * U + uo;
            *(f32x4*)dst       = lo;
            *(f32x4*)(dst + 4) = hi;
        }

        cur = nxt;
    }
}

extern "C" void kernel_launch(void* const* d_in, const int* in_sizes, int n_in,
                              void* d_out, int out_size, void* d_ws, size_t ws_size,
                              hipStream_t stream) {
    const float* x  = (const float*)d_in[0];
    const float* h0 = (const float*)d_in[1];
    const float* c0 = (const float*)d_in[2];
    const float* Wk = (const float*)d_in[3];
    const float* Wr = (const float*)d_in[4];
    const float* b  = (const float*)d_in[5];
    float* out = (float*)d_out;

    _Float16* Wq = (_Float16*)d_ws;   // KC*G4*KPACK*2 = 640 KB

    pack_w<<<KC * 4, 1024, 0, stream>>>(Wr, Wk, Wq);
    lstm_kernel<<<B_TOTAL / BM, 1024, 0, stream>>>(x, h0, c0, Wq, b, out);
}

// Round 11
// 489.408 us; speedup vs baseline: 1.4349x; 1.1135x over previous
//
#include <hip/hip_runtime.h>

typedef _Float16 half8 __attribute__((ext_vector_type(8)));
typedef float f32x4 __attribute__((ext_vector_type(4)));

#define B_TOTAL 32768
#define T 7
#define F 36
#define U 256
#define G4 1024
#define BM 64
#define KC 10          // K chunks of 32: kc 0..7 = h (K=256), kc 8..9 = x (F=36 padded to 64)
#define KPACK 32
#define H_STRIDE 264   // halves; 264*2=528 B rows, 16B-aligned; 2-way bank alias only
#define XS 72          // halves per (t,row) in xs plane; 144 B stride

// Round-0/5 verified W layout: Wq[kc][n][kin] fp16, n = gate*256 + u.
// W = [Wr (256 rows); Wk (36 rows); zeros (28 rows)].
__global__ __launch_bounds__(1024) void pack_w(const float* __restrict__ Wr,
                                               const float* __restrict__ Wk,
                                               _Float16* __restrict__ Wq) {
    const int kc   = blockIdx.x >> 2;
    const int kin0 = (blockIdx.x & 3) * 8;
    const int n    = threadIdx.x;
    _Float16* dst = Wq + ((size_t)kc * G4 + n) * KPACK + kin0;
    #pragma unroll
    for (int j = 0; j < 8; ++j) {
        int k = kc * KPACK + kin0 + j;
        float v = 0.f;
        if (k < U)          v = Wr[(size_t)k * G4 + n];
        else if (k < U + F) v = Wk[(size_t)(k - U) * G4 + n];
        dst[j] = (_Float16)v;
    }
}

__device__ __forceinline__ float fast_sigmoid(float x) {
    return __builtin_amdgcn_rcpf(1.f + __expf(-x));
}
__device__ __forceinline__ float fast_tanh(float x) {
    return 1.f - 2.f * __builtin_amdgcn_rcpf(1.f + __expf(2.f * x));
}

// Persistent LSTM, round-5 structure (275us verified, traffic-clean).
// REGISTER BUDGET NOTE (rounds 6/10 lesson): 1024 threads = 16 waves = 4/SIMD
// -> hard cap 128 regs/lane. acc(64 AGPR) + 64 VGPR = exactly 128. Any
// liveness extension spills to scratch (HBM). Do not add register pipelining.
// Single delta vs round 5: out-stores are NON-TEMPORAL (no L2 allocation).
// Theory: streamed output write-allocations churn L2 and evict the 640KB W
// working set (54MB of W re-fetches at BM=64; catastrophic at BM=32).
__global__ __launch_bounds__(1024) void lstm_kernel(
    const float* __restrict__ x,      // [B,T,F]
    const float* __restrict__ h0,     // [B,U]
    const float* __restrict__ c0,     // [B,U]
    const _Float16* __restrict__ Wq,  // packed [KC][G4][KPACK]
    const float* __restrict__ bias_g, // [G4]
    float* __restrict__ out)          // [B,T,U]
{
    __shared__ __align__(16) _Float16 hbuf[2][BM * H_STRIDE];  // 2 x 33.8 KB
    __shared__ __align__(16) _Float16 xs[T * BM * XS];          // 64.5 KB

    const int tid  = threadIdx.x;
    const int lane = tid & 63;
    const int w    = tid >> 6;     // wave id 0..15 = u-tile
    const int l15  = lane & 15;
    const int q    = lane >> 4;    // 0..3
    const int u0   = w * 16;
    const int b0   = blockIdx.x * BM;

    // --- zero xs (covers the f=36..63 pad the MFMA reads, and row pad) ---
    {
        half8 z = {};
        for (int i = tid * 8; i < T * BM * XS; i += 1024 * 8)
            *(half8*)&xs[i] = z;
    }
    __syncthreads();   // zero visible before fill

    // --- stage h0 -> LDS fp16 ---
    for (int i = tid; i < BM * U; i += 1024) {
        int m = i >> 8, u = i & 255;
        hbuf[0][m * H_STRIDE + u] = (_Float16)h0[(size_t)b0 * U + i];
    }
    // --- stage ALL x for this block's rows (contiguous 64KB global read) ---
    for (int i = tid; i < BM * (T * F); i += 1024) {
        int row = i / (T * F);
        int rem = i - row * (T * F);
        int t   = rem / F;
        int f   = rem - t * F;
        xs[(t * BM + row) * XS + f] = (_Float16)x[(size_t)(b0 + row) * (T * F) + rem];
    }
    // --- c0 into registers: lane holds (u = u0+l15) for rows mt*16+q*4+r ---
    float c[16];
    #pragma unroll
    for (int mt = 0; mt < 4; ++mt)
        #pragma unroll
        for (int r = 0; r < 4; ++r) {
            int row = mt * 16 + q * 4 + r;
            c[mt * 4 + r] = c0[(size_t)(b0 + row) * U + u0 + l15];
        }
    // --- bias per gate ---
    float bv[4];
    #pragma unroll
    for (int g = 0; g < 4; ++g) bv[g] = bias_g[g * U + u0 + l15];

    __syncthreads();   // staging complete

    int cur = 0;
    #pragma unroll 1
    for (int t = 0; t < T; ++t) {
        f32x4 acc[4][4];   // [m_tile][gate]
        #pragma unroll
        for (int mt = 0; mt < 4; ++mt)
            #pragma unroll
            for (int g = 0; g < 4; ++g)
                acc[mt][g] = (f32x4){bv[g], bv[g], bv[g], bv[g]};

        // --- K loop: z[64,1024] = h@Wr + x_t@Wk + b (round-5 verbatim) ---
        #pragma unroll 2
        for (int kc = 0; kc < KC; ++kc) {
            half8 bf[4];
            #pragma unroll
            for (int g = 0; g < 4; ++g) {
                size_t off = ((size_t)kc * G4 + g * U + u0 + l15) * KPACK + q * 8;
                bf[g] = *(const half8*)(Wq + off);
            }
            #pragma unroll
            for (int mt = 0; mt < 4; ++mt) {
                half8 af;
                if (kc < 8)
                    af = *(const half8*)&hbuf[cur][(mt * 16 + l15) * H_STRIDE + kc * 32 + q * 8];
                else
                    af = *(const half8*)&xs[(t * BM + mt * 16 + l15) * XS + (kc - 8) * 32 + q * 8];
                #pragma unroll
                for (int g = 0; g < 4; ++g)
                    acc[mt][g] = __builtin_amdgcn_mfma_f32_16x16x32_f16(af, bf[g], acc[mt][g], 0, 0, 0);
            }
        }

        // --- gates: i,f,g,o for (row,u) all live in the same lane ---
        const int nxt = cur ^ 1;
        #pragma unroll
        for (int mt = 0; mt < 4; ++mt)
            #pragma unroll
            for (int r = 0; r < 4; ++r) {
                float zi = acc[mt][0][r];
                float zf = acc[mt][1][r];
                float zg = acc[mt][2][r];
                float zo = acc[mt][3][r];
                float ig = fast_sigmoid(zi);
                float fg = fast_sigmoid(zf);
                float gg = fast_tanh(zg);
                float og = fast_sigmoid(zo);
                float cn = fg * c[mt * 4 + r] + ig * gg;
                c[mt * 4 + r] = cn;
                float hv = og * fast_tanh(cn);
                int row = mt * 16 + q * 4 + r;
                hbuf[nxt][row * H_STRIDE + u0 + l15] = (_Float16)hv;
            }

        __syncthreads();   // h_{t+1} visible; K-loop readers of hbuf[cur] done

        // --- coalesced NON-TEMPORAL out-store from hbuf[nxt]: consecutive tids
        // -> consecutive 32B -> full 128B lines, nt flag -> no L2 allocation so
        // the streamed output cannot evict the 640KB W working set. Fire-and-
        // forget: overlaps next step's K-loop (next hbuf[nxt] write is one
        // barrier + pipeline past these reads; verified rounds 0/5). ---
        #pragma unroll
        for (int rb = 0; rb < 2; ++rb) {
            int j   = tid + rb * 1024;      // 0..2047 chunks of 8 floats
            int row = j >> 5;
            int uo  = (j & 31) * 8;
            half8 hv = *(const half8*)&hbuf[nxt][row * H_STRIDE + uo];
            f32x4 lo = { (float)hv[0], (float)hv[1], (float)hv[2], (float)hv[3] };
            f32x4 hi = { (float)hv[4], (float)hv[5], (float)hv[6], (float)hv[7] };
            float* dst = out + ((size_t)(b0 + row) * T + t) * U + uo;
            __builtin_nontemporal_store(lo, (f32x4*)dst);
            __builtin_nontemporal_store(hi, (f32x4*)(dst + 4));
        }

        cur = nxt;
    }
}

extern "C" void kernel_launch(void* const* d_in, const int* in_sizes, int n_in,
                              void* d_out, int out_size, void* d_ws, size_t ws_size,
                              hipStream_t stream) {
    const float* x  = (const float*)d_in[0];
    const float* h0 = (const float*)d_in[1];
    const float* c0 = (const float*)d_in[2];
    const float* Wk = (const float*)d_in[3];
    const float* Wr = (const float*)d_in[4];
    const float* b  = (const float*)d_in[5];
    float* out = (float*)d_out;

    _Float16* Wq = (_Float16*)d_ws;   // KC*G4*KPACK*2 = 640 KB

    pack_w<<<KC * 4, 1024, 0, stream>>>(Wr, Wk, Wq);
    lstm_kernel<<<B_TOTAL / BM, 1024, 0, stream>>>(x, h0, c0, Wq, b, out);
}